// Round 8
// baseline (185.946 us; speedup 1.0000x reference)
//
#include <hip/hip_runtime.h>

#define LN 1024
#define FF 128
#define HH 128
#define CC 10
#define DD 34314
#define OFF_W0 0
#define OFF_B0 16384
#define OFF_W1 16512
#define OFF_B1 32896
#define OFF_W2 33024
#define OFF_B2 34304

__global__ void init_delta(float* delta) { *delta = 0.f; }

__device__ __forceinline__ float invmut(const float* h, int node, int par) {
    return 1.f / fmaxf(fabsf(h[node] - h[par]), 1e-7f);
}
__device__ __forceinline__ float sgprf(float v) {
    return __uint_as_float(__builtin_amdgcn_readfirstlane(__float_as_uint(v)));
}

// 22 streams for level-7 subtree s: R[0..7] = path l7..root, R[8..9] = level-8,
// R[10..13] = level-9, R[14..21] = 8 leaves. wgt[r] = owner-gated 1/mut (0 if not owner).
__device__ __forceinline__ void setup22(const float* W, const float* hts, int s,
                                        const float** R, float* wgt) {
    int path[8];
    path[0] = 127 + s;
#pragma unroll
    for (int k = 1; k < 8; ++k) path[k] = (path[k - 1] - 1) >> 1;   // path[7] = 0
#pragma unroll
    for (int k = 0; k < 8; ++k) R[k] = W + (size_t)path[k] * DD;
    const int l8 = 255 + 2 * s;
    R[8] = W + (size_t)l8 * DD;
    R[9] = W + (size_t)(l8 + 1) * DD;
    const int l9 = 511 + 4 * s;
#pragma unroll
    for (int j = 0; j < 4; ++j) R[10 + j] = W + (size_t)(l9 + j) * DD;
    const int lf = 1023 + 8 * s;
#pragma unroll
    for (int q = 0; q < 8; ++q) R[14 + q] = W + (size_t)(lf + q) * DD;

    wgt[0] = sgprf(invmut(hts, path[0], path[1]));                  // unique per s
#pragma unroll
    for (int k = 1; k < 7; ++k)
        wgt[k] = sgprf(((s & ((1 << k) - 1)) == 0) ? invmut(hts, path[k], path[k + 1]) : 0.f);
    wgt[7] = 0.f;                                                   // root: squares separately
    wgt[8] = sgprf(invmut(hts, l8,     path[0]));
    wgt[9] = sgprf(invmut(hts, l8 + 1, path[0]));
#pragma unroll
    for (int j = 0; j < 4; ++j) wgt[10 + j] = sgprf(invmut(hts, l9 + j, l8 + (j >> 1)));
#pragma unroll
    for (int q = 0; q < 8; ++q) wgt[14 + q] = sgprf(invmut(hts, lf + q, l9 + (q >> 1)));
}

// Load one 22-stream batch for iteration `it` into named array `dst`.
#define LOADB(dst, it)                                                        \
    {                                                                         \
        const int f_   = (it) * 32 + fslot;                                   \
        const int idx_ = (f_ << 6) + (ch << 5) + cp;                          \
        _Pragma("unroll")                                                     \
        for (int r = 0; r < 22; ++r) dst[r] = S2[r][idx_];                    \
    }

// Consume one batch: fused delta + tree-combine + per-leaf FMA.
#define CONS(w, it)                                                           \
    {                                                                         \
        const int f_ = (it) * 32 + fslot;                                     \
        _Pragma("unroll")                                                     \
        for (int r = 0; r < 22; ++r)                                          \
            dacc += (fabsf(w[r].x) + fabsf(w[r].y)) * wgt[r];                 \
        sacc += w[7].x * w[7].x + w[7].y * w[7].y;                            \
        float ex = w[0].x, ey = w[0].y;                                       \
        _Pragma("unroll")                                                     \
        for (int k = 1; k < 8; ++k) { ex += w[k].x; ey += w[k].y; }           \
        float e8x[2], e8y[2];                                                 \
        _Pragma("unroll")                                                     \
        for (int j = 0; j < 2; ++j) { e8x[j] = ex + w[8 + j].x; e8y[j] = ey + w[8 + j].y; } \
        float e9x[4], e9y[4];                                                 \
        _Pragma("unroll")                                                     \
        for (int j = 0; j < 4; ++j) { e9x[j] = e8x[j >> 1] + w[10 + j].x; e9y[j] = e8y[j >> 1] + w[10 + j].y; } \
        _Pragma("unroll")                                                     \
        for (int q = 0; q < 8; ++q) {                                         \
            const float tx = e9x[q >> 1] + w[14 + q].x;                       \
            const float ty = e9y[q >> 1] + w[14 + q].y;                       \
            const float xv = ins[q][f_];                                      \
            yx[q] += xv * tx;                                                 \
            yy[q] += xv * ty;                                                 \
        }                                                                     \
    }

// One (subtree s, column-half ch) per block; 1024 threads = 32 col-pairs x 32 f-slots.
template <int OFFW, int OFFB>
__global__ __launch_bounds__(1024, 4) void layer_kernel(const float* __restrict__ W,
                                                        const float* __restrict__ invec,
                                                        const float* __restrict__ hts,
                                                        float* __restrict__ outvec,
                                                        float* __restrict__ delta_out) {
    const int bid  = blockIdx.x;
    const int u    = ((bid & 7) << 5) | (bid >> 3);   // XCD-chunked bijection (256 = 8*32)
    const int s    = u >> 1;
    const int ch   = u & 1;
    const int tid  = threadIdx.x, lane = tid & 63, wv = tid >> 6;
    const int fslot = tid >> 5;                       // 0..31
    const int cp    = tid & 31;                       // col-pair within half

    const float* R[22]; float wgt[22];
    setup22(W, hts, s, R, wgt);
    const float sqm = (s == 0) ? 1.f : 0.f;

    __shared__ float ins[8][FF];
    __shared__ float partF[8 * 32 * 64];              // 64 KB
    __shared__ float ebias[64];
    __shared__ float red[16];

    { const int q = tid >> 7, c = tid & 127; ins[q][c] = invec[(8 * s + q) * FF + c]; }

    float dacc = 0.f, sacc = 0.f;
    if (tid < 64) {                                   // path biases for this col-half
        const int gcol = ch * 64 + tid;
        float eb = 0.f;
#pragma unroll
        for (int k = 0; k < 8; ++k) {
            const float v = R[k][OFFB + gcol];
            eb += v;
            dacc += fabsf(v) * wgt[k];
            if (k == 7) sacc += v * v;
        }
        ebias[tid] = eb;
    }
    __syncthreads();

    const float2* S2[22];
#pragma unroll
    for (int r = 0; r < 22; ++r) S2[r] = reinterpret_cast<const float2*>(R[r] + OFFW);

    float yx[8], yy[8];
#pragma unroll
    for (int q = 0; q < 8; ++q) { yx[q] = 0.f; yy[q] = 0.f; }

    // ---- 2-deep software-pipelined stream loop (4 iterations) ----
    {
        float2 wA[22], wB[22];
        LOADB(wA, 0);
        LOADB(wB, 1);
        CONS(wA, 0);
        LOADB(wA, 2);
        CONS(wB, 1);
        LOADB(wB, 3);
        CONS(wA, 2);
        CONS(wB, 3);
    }

#pragma unroll
    for (int q = 0; q < 8; ++q)
        *reinterpret_cast<float2*>(&partF[((q * 32 + fslot) << 6) + 2 * cp]) = make_float2(yx[q], yy[q]);
    __syncthreads();

    if (tid < 512) {                                  // reduce + leaf-level biases + relu + store
        const int q = tid >> 6, col = tid & 63;       // q wave-uniform
        const int gcol = ch * 64 + col;
        const float v8 = R[8  + (q >> 2)][OFFB + gcol];
        const float v9 = R[10 + (q >> 1)][OFFB + gcol];
        const float vl = R[14 + q      ][OFFB + gcol];
        if ((q & 3) == 0) dacc += fabsf(v8) * wgt[8  + (q >> 2)];
        if ((q & 1) == 0) dacc += fabsf(v9) * wgt[10 + (q >> 1)];
        dacc += fabsf(vl) * wgt[14 + q];
        float sum = ebias[col] + v8 + v9 + vl;
#pragma unroll
        for (int fs = 0; fs < 32; ++fs) sum += partF[((q * 32 + fs) << 6) + col];
        outvec[(8 * s + q) * HH + gcol] = fmaxf(sum, 0.f);
    }

    float v = dacc + sacc * sqm;
    for (int o = 32; o > 0; o >>= 1) v += __shfl_down(v, o);
    if (lane == 0) red[wv] = v;
    __syncthreads();
    if (tid == 0) {
        float t = 0.f;
#pragma unroll
        for (int wq = 0; wq < 16; ++wq) t += red[wq];
        atomicAdd(delta_out, t);
    }
}

// Layer 2 + softmax + W2/b2 delta. One block per subtree (128 blocks).
__global__ __launch_bounds__(1024, 4) void head_kernel(const float* __restrict__ W,
                                                       const float* __restrict__ ws_h1,
                                                       const float* __restrict__ hts,
                                                       float* __restrict__ out,
                                                       float* __restrict__ delta_out) {
    const int bid = blockIdx.x;
    const int s   = ((bid & 7) << 4) | (bid >> 3);    // 128 = 8*16
    const int tid = threadIdx.x, lane = tid & 63, wv = tid >> 6;

    const float* R[22]; float wgt[22];
    setup22(W, hts, s, R, wgt);
    const float sqm = (s == 0) ? 1.f : 0.f;

    __shared__ float ins[8][HH];
    __shared__ float lgts[8][CC];
    __shared__ float red[16];

    { const int q = tid >> 7, c = tid & 127; ins[q][c] = ws_h1[(8 * s + q) * HH + c]; }
    if (tid < 8 * CC) ((float*)lgts)[tid] = 0.f;

    float dacc = 0.f, sacc = 0.f;
    __syncthreads();

    if (tid < 640) {                                  // 640 float2 = W2 region
        const int pos = tid;
        float2 w[22];
#pragma unroll
        for (int r = 0; r < 22; ++r)
            w[r] = *reinterpret_cast<const float2*>(R[r] + OFF_W2 + 2 * pos);
#pragma unroll
        for (int r = 0; r < 22; ++r)
            dacc += (fabsf(w[r].x) + fabsf(w[r].y)) * wgt[r];
        sacc += w[7].x * w[7].x + w[7].y * w[7].y;
        float ex = w[0].x, ey = w[0].y;
#pragma unroll
        for (int k = 1; k < 8; ++k) { ex += w[k].x; ey += w[k].y; }
        float e8x[2], e8y[2];
#pragma unroll
        for (int j = 0; j < 2; ++j) { e8x[j] = ex + w[8 + j].x; e8y[j] = ey + w[8 + j].y; }
        float e9x[4], e9y[4];
#pragma unroll
        for (int j = 0; j < 4; ++j) { e9x[j] = e8x[j >> 1] + w[10 + j].x; e9y[j] = e8y[j >> 1] + w[10 + j].y; }
        const int h  = pos / 5;
        const int c0 = 2 * (pos - 5 * h);
#pragma unroll
        for (int q = 0; q < 8; ++q) {
            const float tx = e9x[q >> 1] + w[14 + q].x;
            const float ty = e9y[q >> 1] + w[14 + q].y;
            const float hv = ins[q][h];
            atomicAdd(&lgts[q][c0],     hv * tx);
            atomicAdd(&lgts[q][c0 + 1], hv * ty);
        }
    }
    __syncthreads();
    if (tid < 80) {                                   // b2 effective + delta
        const int q = tid / 10, c = tid - 10 * q;
        float eb = 0.f;
#pragma unroll
        for (int k = 0; k < 8; ++k) {
            const float v = R[k][OFF_B2 + c];
            eb += v;
            if (q == 0) { dacc += fabsf(v) * wgt[k]; if (k == 7) sacc += v * v; }
        }
        const float v8 = R[8  + (q >> 2)][OFF_B2 + c];
        const float v9 = R[10 + (q >> 1)][OFF_B2 + c];
        const float vl = R[14 + q      ][OFF_B2 + c];
        if ((q & 3) == 0) dacc += fabsf(v8) * wgt[8  + (q >> 2)];
        if ((q & 1) == 0) dacc += fabsf(v9) * wgt[10 + (q >> 1)];
        dacc += fabsf(vl) * wgt[14 + q];
        lgts[q][c] += eb + v8 + v9 + vl;
    }
    __syncthreads();

    if (tid < 8) {
        const int q = tid;
        float mx = lgts[q][0];
#pragma unroll
        for (int c = 1; c < CC; ++c) mx = fmaxf(mx, lgts[q][c]);
        float e[CC], ssum = 0.f;
#pragma unroll
        for (int c = 0; c < CC; ++c) { e[c] = expf(lgts[q][c] - mx); ssum += e[c]; }
        const float inv = 1.f / ssum;
#pragma unroll
        for (int c = 0; c < CC; ++c) out[(8 * s + q) * CC + c] = e[c] * inv;
    }

    float v = dacc + sacc * sqm;
    for (int o = 32; o > 0; o >>= 1) v += __shfl_down(v, o);
    if (lane == 0) red[wv] = v;
    __syncthreads();
    if (tid == 0) {
        float t = 0.f;
#pragma unroll
        for (int wq = 0; wq < 16; ++wq) t += red[wq];
        atomicAdd(delta_out, t);
    }
}

extern "C" void kernel_launch(void* const* d_in, const int* in_sizes, int n_in,
                              void* d_out, int out_size, void* d_ws, size_t ws_size,
                              hipStream_t stream) {
    const float* x       = (const float*)d_in[0];   // (1024, 128)
    const float* W       = (const float*)d_in[1];   // (2047, 34314)
    const float* heights = (const float*)d_in[2];   // (2047,)

    float* out   = (float*)d_out;
    float* delta = (float*)d_out + LN * CC;
    float* ws_h0 = (float*)d_ws;                    // 1024*128 floats = 512 KB
    float* ws_h1 = (float*)d_ws + LN * HH;          // 512 KB

    init_delta<<<1, 1, 0, stream>>>(delta);
    layer_kernel<OFF_W0, OFF_B0><<<256, 1024, 0, stream>>>(W, x, heights, ws_h0, delta);
    layer_kernel<OFF_W1, OFF_B1><<<256, 1024, 0, stream>>>(W, ws_h0, heights, ws_h1, delta);
    head_kernel<<<128, 1024, 0, stream>>>(W, ws_h1, heights, out, delta);
}

// Round 9
// 174.403 us; speedup vs baseline: 1.0662x; 1.0662x over previous
//
#include <hip/hip_runtime.h>

#define LN 1024
#define FF 128
#define HH 128
#define CC 10
#define DD 34314
#define OFF_W0 0
#define OFF_B0 16384
#define OFF_W1 16512
#define OFF_B1 32896
#define OFF_W2 33024
#define OFF_B2 34304

__global__ void init_delta(float* delta) { *delta = 0.f; }

__device__ __forceinline__ float invmut(const float* h, int node, int par) {
    return 1.f / fmaxf(fabsf(h[node] - h[par]), 1e-7f);
}
__device__ __forceinline__ float sgprf(float v) {
    return __uint_as_float(__builtin_amdgcn_readfirstlane(__float_as_uint(v)));
}

// 22 streams for level-7 subtree s: R[0..7] = path l7..root, R[8..9] = level-8,
// R[10..13] = level-9, R[14..21] = 8 leaves. wgt[r] = owner-gated 1/mut (0 if not owner).
__device__ __forceinline__ void setup22(const float* W, const float* hts, int s,
                                        const float** R, float* wgt) {
    int path[8];
    path[0] = 127 + s;
#pragma unroll
    for (int k = 1; k < 8; ++k) path[k] = (path[k - 1] - 1) >> 1;   // path[7] = 0
#pragma unroll
    for (int k = 0; k < 8; ++k) R[k] = W + (size_t)path[k] * DD;
    const int l8 = 255 + 2 * s;
    R[8] = W + (size_t)l8 * DD;
    R[9] = W + (size_t)(l8 + 1) * DD;
    const int l9 = 511 + 4 * s;
#pragma unroll
    for (int j = 0; j < 4; ++j) R[10 + j] = W + (size_t)(l9 + j) * DD;
    const int lf = 1023 + 8 * s;
#pragma unroll
    for (int q = 0; q < 8; ++q) R[14 + q] = W + (size_t)(lf + q) * DD;

    wgt[0] = sgprf(invmut(hts, path[0], path[1]));                  // unique per s
#pragma unroll
    for (int k = 1; k < 7; ++k)
        wgt[k] = sgprf(((s & ((1 << k) - 1)) == 0) ? invmut(hts, path[k], path[k + 1]) : 0.f);
    wgt[7] = 0.f;                                                   // root: squares separately
    wgt[8] = sgprf(invmut(hts, l8,     path[0]));
    wgt[9] = sgprf(invmut(hts, l8 + 1, path[0]));
#pragma unroll
    for (int j = 0; j < 4; ++j) wgt[10 + j] = sgprf(invmut(hts, l9 + j, l8 + (j >> 1)));
#pragma unroll
    for (int q = 0; q < 8; ++q) wgt[14 + q] = sgprf(invmut(hts, lf + q, l9 + (q >> 1)));
}

// Load one 22-stream batch for iteration `it` into named array `dst`.
#define LOADB(dst, it)                                                        \
    {                                                                         \
        const int f_   = (it) * 32 + fslot;                                   \
        const int idx_ = (f_ << 6) + (ch << 5) + cp;                          \
        _Pragma("unroll")                                                     \
        for (int r = 0; r < 22; ++r) dst[r] = S2[r][idx_];                    \
    }

// Consume one batch: fused delta + tree-combine + per-leaf FMA.
#define CONS(w, it)                                                           \
    {                                                                         \
        const int f_ = (it) * 32 + fslot;                                     \
        _Pragma("unroll")                                                     \
        for (int r = 0; r < 22; ++r)                                          \
            dacc += (fabsf(w[r].x) + fabsf(w[r].y)) * wgt[r];                 \
        sacc += w[7].x * w[7].x + w[7].y * w[7].y;                            \
        float ex = w[0].x, ey = w[0].y;                                       \
        _Pragma("unroll")                                                     \
        for (int k = 1; k < 8; ++k) { ex += w[k].x; ey += w[k].y; }           \
        float e8x[2], e8y[2];                                                 \
        _Pragma("unroll")                                                     \
        for (int j = 0; j < 2; ++j) { e8x[j] = ex + w[8 + j].x; e8y[j] = ey + w[8 + j].y; } \
        float e9x[4], e9y[4];                                                 \
        _Pragma("unroll")                                                     \
        for (int j = 0; j < 4; ++j) { e9x[j] = e8x[j >> 1] + w[10 + j].x; e9y[j] = e8y[j >> 1] + w[10 + j].y; } \
        _Pragma("unroll")                                                     \
        for (int q = 0; q < 8; ++q) {                                         \
            const float tx = e9x[q >> 1] + w[14 + q].x;                       \
            const float ty = e9y[q >> 1] + w[14 + q].y;                       \
            const float xv = ins[q][f_];                                      \
            yx[q] += xv * tx;                                                 \
            yy[q] += xv * ty;                                                 \
        }                                                                     \
    }

// One (subtree s, column-half ch) per block; 1024 threads = 32 col-pairs x 32 f-slots.
// amdgpu_waves_per_eu(4,4): register budget 128 VGPR (4 waves/EU), occupancy target
// capped so the scheduler does NOT squeeze to 64 VGPR (R8's spill catastrophe).
template <int OFFW, int OFFB>
__global__ __launch_bounds__(1024)
__attribute__((amdgpu_waves_per_eu(4, 4)))
void layer_kernel(const float* __restrict__ W,
                  const float* __restrict__ invec,
                  const float* __restrict__ hts,
                  float* __restrict__ outvec,
                  float* __restrict__ delta_out) {
    const int bid  = blockIdx.x;
    const int u    = ((bid & 7) << 5) | (bid >> 3);   // XCD-chunked bijection (256 = 8*32)
    const int s    = u >> 1;
    const int ch   = u & 1;
    const int tid  = threadIdx.x, lane = tid & 63, wv = tid >> 6;
    const int fslot = tid >> 5;                       // 0..31
    const int cp    = tid & 31;                       // col-pair within half

    const float* R[22]; float wgt[22];
    setup22(W, hts, s, R, wgt);
    const float sqm = (s == 0) ? 1.f : 0.f;

    __shared__ float ins[8][FF];
    __shared__ float partF[8 * 32 * 64];              // 64 KB
    __shared__ float ebias[64];
    __shared__ float red[16];

    { const int q = tid >> 7, c = tid & 127; ins[q][c] = invec[(8 * s + q) * FF + c]; }

    float dacc = 0.f, sacc = 0.f;
    if (tid < 64) {                                   // path biases for this col-half
        const int gcol = ch * 64 + tid;
        float eb = 0.f;
#pragma unroll
        for (int k = 0; k < 8; ++k) {
            const float v = R[k][OFFB + gcol];
            eb += v;
            dacc += fabsf(v) * wgt[k];
            if (k == 7) sacc += v * v;
        }
        ebias[tid] = eb;
    }
    __syncthreads();

    const float2* S2[22];
#pragma unroll
    for (int r = 0; r < 22; ++r) S2[r] = reinterpret_cast<const float2*>(R[r] + OFFW);

    float yx[8], yy[8];
#pragma unroll
    for (int q = 0; q < 8; ++q) { yx[q] = 0.f; yy[q] = 0.f; }

    // ---- 2-deep software-pipelined stream loop (4 iterations) ----
    {
        float2 wA[22], wB[22];
        LOADB(wA, 0);
        LOADB(wB, 1);
        CONS(wA, 0);
        LOADB(wA, 2);
        CONS(wB, 1);
        LOADB(wB, 3);
        CONS(wA, 2);
        CONS(wB, 3);
    }

#pragma unroll
    for (int q = 0; q < 8; ++q)
        *reinterpret_cast<float2*>(&partF[((q * 32 + fslot) << 6) + 2 * cp]) = make_float2(yx[q], yy[q]);
    __syncthreads();

    if (tid < 512) {                                  // reduce + leaf-level biases + relu + store
        const int q = tid >> 6, col = tid & 63;       // q wave-uniform
        const int gcol = ch * 64 + col;
        const float v8 = R[8  + (q >> 2)][OFFB + gcol];
        const float v9 = R[10 + (q >> 1)][OFFB + gcol];
        const float vl = R[14 + q      ][OFFB + gcol];
        if ((q & 3) == 0) dacc += fabsf(v8) * wgt[8  + (q >> 2)];
        if ((q & 1) == 0) dacc += fabsf(v9) * wgt[10 + (q >> 1)];
        dacc += fabsf(vl) * wgt[14 + q];
        float sum = ebias[col] + v8 + v9 + vl;
#pragma unroll
        for (int fs = 0; fs < 32; ++fs) sum += partF[((q * 32 + fs) << 6) + col];
        outvec[(8 * s + q) * HH + gcol] = fmaxf(sum, 0.f);
    }

    float v = dacc + sacc * sqm;
    for (int o = 32; o > 0; o >>= 1) v += __shfl_down(v, o);
    if (lane == 0) red[wv] = v;
    __syncthreads();
    if (tid == 0) {
        float t = 0.f;
#pragma unroll
        for (int wq = 0; wq < 16; ++wq) t += red[wq];
        atomicAdd(delta_out, t);
    }
}

// Layer 2 + softmax + W2/b2 delta. One block per subtree (128 blocks).
__global__ __launch_bounds__(1024, 4) void head_kernel(const float* __restrict__ W,
                                                       const float* __restrict__ ws_h1,
                                                       const float* __restrict__ hts,
                                                       float* __restrict__ out,
                                                       float* __restrict__ delta_out) {
    const int bid = blockIdx.x;
    const int s   = ((bid & 7) << 4) | (bid >> 3);    // 128 = 8*16
    const int tid = threadIdx.x, lane = tid & 63, wv = tid >> 6;

    const float* R[22]; float wgt[22];
    setup22(W, hts, s, R, wgt);
    const float sqm = (s == 0) ? 1.f : 0.f;

    __shared__ float ins[8][HH];
    __shared__ float lgts[8][CC];
    __shared__ float red[16];

    { const int q = tid >> 7, c = tid & 127; ins[q][c] = ws_h1[(8 * s + q) * HH + c]; }
    if (tid < 8 * CC) ((float*)lgts)[tid] = 0.f;

    float dacc = 0.f, sacc = 0.f;
    __syncthreads();

    if (tid < 640) {                                  // 640 float2 = W2 region
        const int pos = tid;
        float2 w[22];
#pragma unroll
        for (int r = 0; r < 22; ++r)
            w[r] = *reinterpret_cast<const float2*>(R[r] + OFF_W2 + 2 * pos);
#pragma unroll
        for (int r = 0; r < 22; ++r)
            dacc += (fabsf(w[r].x) + fabsf(w[r].y)) * wgt[r];
        sacc += w[7].x * w[7].x + w[7].y * w[7].y;
        float ex = w[0].x, ey = w[0].y;
#pragma unroll
        for (int k = 1; k < 8; ++k) { ex += w[k].x; ey += w[k].y; }
        float e8x[2], e8y[2];
#pragma unroll
        for (int j = 0; j < 2; ++j) { e8x[j] = ex + w[8 + j].x; e8y[j] = ey + w[8 + j].y; }
        float e9x[4], e9y[4];
#pragma unroll
        for (int j = 0; j < 4; ++j) { e9x[j] = e8x[j >> 1] + w[10 + j].x; e9y[j] = e8y[j >> 1] + w[10 + j].y; }
        const int h  = pos / 5;
        const int c0 = 2 * (pos - 5 * h);
#pragma unroll
        for (int q = 0; q < 8; ++q) {
            const float tx = e9x[q >> 1] + w[14 + q].x;
            const float ty = e9y[q >> 1] + w[14 + q].y;
            const float hv = ins[q][h];
            atomicAdd(&lgts[q][c0],     hv * tx);
            atomicAdd(&lgts[q][c0 + 1], hv * ty);
        }
    }
    __syncthreads();
    if (tid < 80) {                                   // b2 effective + delta
        const int q = tid / 10, c = tid - 10 * q;
        float eb = 0.f;
#pragma unroll
        for (int k = 0; k < 8; ++k) {
            const float v = R[k][OFF_B2 + c];
            eb += v;
            if (q == 0) { dacc += fabsf(v) * wgt[k]; if (k == 7) sacc += v * v; }
        }
        const float v8 = R[8  + (q >> 2)][OFF_B2 + c];
        const float v9 = R[10 + (q >> 1)][OFF_B2 + c];
        const float vl = R[14 + q      ][OFF_B2 + c];
        if ((q & 3) == 0) dacc += fabsf(v8) * wgt[8  + (q >> 2)];
        if ((q & 1) == 0) dacc += fabsf(v9) * wgt[10 + (q >> 1)];
        dacc += fabsf(vl) * wgt[14 + q];
        lgts[q][c] += eb + v8 + v9 + vl;
    }
    __syncthreads();

    if (tid < 8) {
        const int q = tid;
        float mx = lgts[q][0];
#pragma unroll
        for (int c = 1; c < CC; ++c) mx = fmaxf(mx, lgts[q][c]);
        float e[CC], ssum = 0.f;
#pragma unroll
        for (int c = 0; c < CC; ++c) { e[c] = expf(lgts[q][c] - mx); ssum += e[c]; }
        const float inv = 1.f / ssum;
#pragma unroll
        for (int c = 0; c < CC; ++c) out[(8 * s + q) * CC + c] = e[c] * inv;
    }

    float v = dacc + sacc * sqm;
    for (int o = 32; o > 0; o >>= 1) v += __shfl_down(v, o);
    if (lane == 0) red[wv] = v;
    __syncthreads();
    if (tid == 0) {
        float t = 0.f;
#pragma unroll
        for (int wq = 0; wq < 16; ++wq) t += red[wq];
        atomicAdd(delta_out, t);
    }
}

extern "C" void kernel_launch(void* const* d_in, const int* in_sizes, int n_in,
                              void* d_out, int out_size, void* d_ws, size_t ws_size,
                              hipStream_t stream) {
    const float* x       = (const float*)d_in[0];   // (1024, 128)
    const float* W       = (const float*)d_in[1];   // (2047, 34314)
    const float* heights = (const float*)d_in[2];   // (2047,)

    float* out   = (float*)d_out;
    float* delta = (float*)d_out + LN * CC;
    float* ws_h0 = (float*)d_ws;                    // 1024*128 floats = 512 KB
    float* ws_h1 = (float*)d_ws + LN * HH;          // 512 KB

    init_delta<<<1, 1, 0, stream>>>(delta);
    layer_kernel<OFF_W0, OFF_B0><<<256, 1024, 0, stream>>>(W, x, heights, ws_h0, delta);
    layer_kernel<OFF_W1, OFF_B1><<<256, 1024, 0, stream>>>(W, ws_h0, heights, ws_h1, delta);
    head_kernel<<<128, 1024, 0, stream>>>(W, ws_h1, heights, out, delta);
}

// Round 10
// 96.342 us; speedup vs baseline: 1.9301x; 1.8103x over previous
//
#include <hip/hip_runtime.h>

#define LN 1024
#define FF 128
#define HH 128
#define CC 10
#define DD 34314
#define OFF_W0 0
#define OFF_B0 16384
#define OFF_W1 16512
#define OFF_B1 32896
#define OFF_W2 33024
#define OFF_B2 34304

__global__ void init_delta(float* delta) { *delta = 0.f; }

__device__ __forceinline__ float invmut(const float* h, int node, int par) {
    return 1.f / fmaxf(fabsf(h[node] - h[par]), 1e-7f);
}

// One block = one level-8 subtree (4 leaves), 1024 threads.
// 15 row-streams: R[0..8] = level-8 ancestor .. root, R[9..10] = level-9 pair,
// R[11..14] = 4 leaves. Distributive matvec; delta fully fused via per-stream
// weights wgt[r] (= owner ? 1/mut : 0), root sum-of-squares masked at the end.
// waves_per_eu(4,4): grid is 1 block/CU (16 waves = 4/EU) so max=4 costs nothing,
// but it pins the VGPR budget at 128 so the 15-stream batch pipelines without
// the default occupancy heuristic squeezing to 64 VGPR (R3 counter evidence).
__global__ __launch_bounds__(1024, 4)
__attribute__((amdgpu_waves_per_eu(4, 4)))
void fused_kernel(const float* __restrict__ W,
                  const float* __restrict__ x,
                  const float* __restrict__ heights,
                  float* __restrict__ out,
                  float* __restrict__ delta_out) {
    const int bid  = blockIdx.x;
    const int m    = ((bid & 7) << 5) | (bid >> 3);   // XCD-chunked bijection (256 = 8 XCD * 32)
    const int tid  = threadIdx.x;
    const int lane = tid & 63;
    const int wv   = tid >> 6;          // 0..15 : f-range [8*wv, 8*wv+8)
    const int j2   = lane;              // column pair (2*j2, 2*j2+1)

    int path[9];
    {
        int n = 255 + m;
#pragma unroll
        for (int k = 0; k < 9; ++k) { path[k] = n; n = (n - 1) >> 1; }
    }
    const float* R[15];
#pragma unroll
    for (int k = 0; k < 9; ++k) R[k] = W + (size_t)path[k] * DD;
    const int n9a = 511 + 2 * m, n9b = n9a + 1;
    R[9]  = W + (size_t)n9a * DD;
    R[10] = W + (size_t)n9b * DD;
#pragma unroll
    for (int q = 0; q < 4; ++q) R[11 + q] = W + (size_t)(1023 + 4 * m + q) * DD;

    float wgt[15];
#pragma unroll
    for (int k = 0; k < 8; ++k)
        wgt[k] = ((m & ((1 << k) - 1)) == 0) ? invmut(heights, path[k], path[k + 1]) : 0.f;
    wgt[8]  = 0.f;                       // root: no l1 term (sum-of-squares instead)
    wgt[9]  = invmut(heights, n9a, path[0]);
    wgt[10] = invmut(heights, n9b, path[0]);
#pragma unroll
    for (int q = 0; q < 4; ++q)
        wgt[11 + q] = invmut(heights, 1023 + 4 * m + q, (q < 2) ? n9a : n9b);
    const float sqmask = (m == 0) ? 1.f : 0.f;

    __shared__ float ins[4][HH];         // current layer input per leaf
    __shared__ float part[4][16][HH];    // matvec partials [leaf][wave][col]  (32 KB)
    __shared__ float lgts[4][CC];
    __shared__ float red[16];

    if (tid < 512) { const int q = tid >> 7, t = tid & 127; ins[q][t] = x[(4 * m + q) * FF + t]; }
    if (tid < 4 * CC) ((float*)lgts)[tid] = 0.f;

    float dacc = 0.f, sacc = 0.f;
    __syncthreads();

    // ---------------- layers 0 and 1 (128 -> 128) ----------------
#pragma unroll
    for (int layer = 0; layer < 2; ++layer) {
        const int offW = layer ? OFF_W1 : OFF_W0;
        const int offB = layer ? OFF_B1 : OFF_B0;
        const float2* S2[15];
#pragma unroll
        for (int r = 0; r < 15; ++r) S2[r] = reinterpret_cast<const float2*>(R[r] + offW);

        float yx[4], yy[4];
#pragma unroll
        for (int q = 0; q < 4; ++q) { yx[q] = 0.f; yy[q] = 0.f; }

#pragma unroll 2
        for (int i = 0; i < 8; ++i) {
            const int f   = (wv << 3) + i;
            const int off = (f << 6) + j2;
            float ex = 0.f, ey = 0.f;
#pragma unroll
            for (int k = 0; k < 9; ++k) {
                const float2 w = S2[k][off];
                ex += w.x; ey += w.y;
                dacc += (fabsf(w.x) + fabsf(w.y)) * wgt[k];
                if (k == 8) sacc += w.x * w.x + w.y * w.y;
            }
            const float2 wa0 = S2[9][off];
            const float2 wa1 = S2[10][off];
            dacc += (fabsf(wa0.x) + fabsf(wa0.y)) * wgt[9];
            dacc += (fabsf(wa1.x) + fabsf(wa1.y)) * wgt[10];
#pragma unroll
            for (int q = 0; q < 4; ++q) {
                const float2 wb = S2[11 + q][off];
                dacc += (fabsf(wb.x) + fabsf(wb.y)) * wgt[11 + q];
                const float2 wa = (q < 2) ? wa0 : wa1;
                const float xv = ins[q][f];
                yx[q] += xv * (ex + wa.x + wb.x);
                yy[q] += xv * (ey + wa.y + wb.y);
            }
        }
#pragma unroll
        for (int q = 0; q < 4; ++q)
            *reinterpret_cast<float2*>(&part[q][wv][2 * j2]) = make_float2(yx[q], yy[q]);
        __syncthreads();

        if (tid < 512) {
            const int q = tid >> 7, col = tid & 127;   // q uniform per wave
            float eb = 0.f;
#pragma unroll
            for (int k = 0; k < 9; ++k) {
                const float v = R[k][offB + col];
                eb += v;
                if (q == 0) { dacc += fabsf(v) * wgt[k]; if (k == 8) sacc += v * v; }
            }
            const float a0 = R[9][offB + col];
            const float a1 = R[10][offB + col];
            if (q == 0) dacc += fabsf(a0) * wgt[9];
            if (q == 2) dacc += fabsf(a1) * wgt[10];
            const float bq = R[11 + q][offB + col];
            dacc += fabsf(bq) * wgt[11 + q];
            float s = eb + ((q < 2) ? a0 : a1) + bq;
#pragma unroll
            for (int w = 0; w < 16; ++w) s += part[q][w][col];
            ins[q][col] = fmaxf(s, 0.f);
        }
        __syncthreads();
    }

    // ---------------- layer 2 (128 -> 10) ----------------
    {
        const float2* S2[15];
#pragma unroll
        for (int r = 0; r < 15; ++r) S2[r] = reinterpret_cast<const float2*>(R[r] + OFF_W2);
        if (tid < 640) {                 // 640 float2 = 1280 weights per row
            const int h  = tid / 5;
            const int c0 = (tid - 5 * h) * 2;
            float ex = 0.f, ey = 0.f;
#pragma unroll
            for (int k = 0; k < 9; ++k) {
                const float2 w = S2[k][tid];
                ex += w.x; ey += w.y;
                dacc += (fabsf(w.x) + fabsf(w.y)) * wgt[k];
                if (k == 8) sacc += w.x * w.x + w.y * w.y;
            }
            const float2 wa0 = S2[9][tid];
            const float2 wa1 = S2[10][tid];
            dacc += (fabsf(wa0.x) + fabsf(wa0.y)) * wgt[9];
            dacc += (fabsf(wa1.x) + fabsf(wa1.y)) * wgt[10];
#pragma unroll
            for (int q = 0; q < 4; ++q) {
                const float2 wb = S2[11 + q][tid];
                dacc += (fabsf(wb.x) + fabsf(wb.y)) * wgt[11 + q];
                const float2 wa = (q < 2) ? wa0 : wa1;
                const float hv = ins[q][h];
                atomicAdd(&lgts[q][c0],     hv * (ex + wa.x + wb.x));
                atomicAdd(&lgts[q][c0 + 1], hv * (ey + wa.y + wb.y));
            }
        }
        __syncthreads();
        if (tid < CC) {
            float eb = 0.f;
#pragma unroll
            for (int k = 0; k < 9; ++k) {
                const float v = R[k][OFF_B2 + tid];
                eb += v;
                dacc += fabsf(v) * wgt[k];
                if (k == 8) sacc += v * v;
            }
            const float a0 = R[9][OFF_B2 + tid];
            const float a1 = R[10][OFF_B2 + tid];
            dacc += fabsf(a0) * wgt[9] + fabsf(a1) * wgt[10];
#pragma unroll
            for (int q = 0; q < 4; ++q) {
                const float bq = R[11 + q][OFF_B2 + tid];
                dacc += fabsf(bq) * wgt[11 + q];
                lgts[q][tid] += eb + ((q < 2) ? a0 : a1) + bq;
            }
        }
        __syncthreads();
    }

    // ---------------- softmax (one thread per leaf) ----------------
    if (tid < 4) {
        const int q = tid;
        float mx = lgts[q][0];
#pragma unroll
        for (int c = 1; c < CC; ++c) mx = fmaxf(mx, lgts[q][c]);
        float e[CC], s = 0.f;
#pragma unroll
        for (int c = 0; c < CC; ++c) { e[c] = expf(lgts[q][c] - mx); s += e[c]; }
        const float inv = 1.f / s;
#pragma unroll
        for (int c = 0; c < CC; ++c) out[(4 * m + q) * CC + c] = e[c] * inv;
    }

    // ---------------- delta reduce: one weighted accumulator ----------------
    float v = dacc + sacc * sqmask;
    for (int o = 32; o > 0; o >>= 1) v += __shfl_down(v, o);
    if (lane == 0) red[wv] = v;
    __syncthreads();
    if (tid == 0) {
        float s = 0.f;
#pragma unroll
        for (int w = 0; w < 16; ++w) s += red[w];
        atomicAdd(delta_out, s);
    }
}

extern "C" void kernel_launch(void* const* d_in, const int* in_sizes, int n_in,
                              void* d_out, int out_size, void* d_ws, size_t ws_size,
                              hipStream_t stream) {
    const float* x       = (const float*)d_in[0];   // (1024, 128)
    const float* W       = (const float*)d_in[1];   // (2047, 34314)
    const float* heights = (const float*)d_in[2];   // (2047,)

    float* out   = (float*)d_out;
    float* delta = (float*)d_out + LN * CC;

    init_delta<<<1, 1, 0, stream>>>(delta);
    fused_kernel<<<256, 1024, 0, stream>>>(W, x, heights, out, delta);
}